// Round 1
// baseline (576.004 us; speedup 1.0000x reference)
//
#include <hip/hip_runtime.h>
#include <cmath>

constexpr int B = 32, T = 1024, J = 256, D = 512;

// ---- workspace layout (float offsets) ----
constexpr size_t OFF_S   = 0;                               // S[b,t,j]
constexpr size_t OFF_QP  = OFF_S  + (size_t)B * T * J;      // query*w3
constexpr size_t OFF_RT  = OFF_QP + (size_t)B * J * D;      // context@w1
constexpr size_t OFF_CT  = OFF_RT + (size_t)B * T;          // query@w2
constexpr size_t OFF_M   = OFF_CT + (size_t)B * J;          // col max over t
constexpr size_t OFF_IL  = OFF_M  + (size_t)B * J;          // 1/col sumexp
constexpr size_t OFF_RM  = OFF_IL + (size_t)B * J;          // row max over j
constexpr size_t OFF_BT  = OFF_RM + (size_t)B * T;          // b_t softmax
constexpr size_t OFF_H   = OFF_BT + (size_t)B * T;          // h[b,d]
constexpr size_t OFF_PM  = OFF_H  + (size_t)B * D;          // partial col max
constexpr size_t OFF_PL  = OFF_PM + (size_t)B * 16 * J;     // partial col sumexp

// ---------- rt[r] = context_row . w1 ----------
__global__ void k_rowdot(const float* __restrict__ src, const float* __restrict__ w,
                         float* __restrict__ out, int nrows) {
  int wid = threadIdx.x >> 6, lane = threadIdx.x & 63;
  int row = blockIdx.x * 4 + wid;
  if (row >= nrows) return;
  const float4* s4 = (const float4*)(src + (size_t)row * D);
  const float4* w4 = (const float4*)w;
  float4 a0 = s4[lane * 2], a1 = s4[lane * 2 + 1];
  float4 b0 = w4[lane * 2], b1 = w4[lane * 2 + 1];
  float acc = a0.x*b0.x + a0.y*b0.y + a0.z*b0.z + a0.w*b0.w
            + a1.x*b1.x + a1.y*b1.y + a1.z*b1.z + a1.w*b1.w;
  #pragma unroll
  for (int off = 32; off; off >>= 1) acc += __shfl_down(acc, off);
  if (lane == 0) out[row] = acc;
}

// ---------- ct[r] = query_row . w2 ; Qp = query * w3 ----------
__global__ void k_prep(const float* __restrict__ query, const float* __restrict__ w_alpha,
                       float* __restrict__ ct, float* __restrict__ Qp) {
  int wid = threadIdx.x >> 6, lane = threadIdx.x & 63;
  int row = blockIdx.x * 4 + wid;   // 8192 rows
  const float4* q4 = (const float4*)(query + (size_t)row * D);
  const float4* w2 = (const float4*)(w_alpha + D);
  const float4* w3 = (const float4*)(w_alpha + 2 * D);
  float4* o4 = (float4*)(Qp + (size_t)row * D);
  float4 a0 = q4[lane*2], a1 = q4[lane*2+1];
  float4 b0 = w2[lane*2], b1 = w2[lane*2+1];
  float4 c0 = w3[lane*2], c1 = w3[lane*2+1];
  float acc = a0.x*b0.x + a0.y*b0.y + a0.z*b0.z + a0.w*b0.w
            + a1.x*b1.x + a1.y*b1.y + a1.z*b1.z + a1.w*b1.w;
  o4[lane*2]   = make_float4(a0.x*c0.x, a0.y*c0.y, a0.z*c0.z, a0.w*c0.w);
  o4[lane*2+1] = make_float4(a1.x*c1.x, a1.y*c1.y, a1.z*c1.z, a1.w*c1.w);
  #pragma unroll
  for (int off = 32; off; off >>= 1) acc += __shfl_down(acc, off);
  if (lane == 0) ct[row] = acc;
}

// ---------- S = context @ Qp^T + rt + ct  (batched, M=1024 N=256 K=512) ----------
__global__ __launch_bounds__(256)
void k_sgemm(const float* __restrict__ C, const float* __restrict__ Qp,
             const float* __restrict__ rt, const float* __restrict__ ct,
             float* __restrict__ S) {
  constexpr int BM = 128, BN = 128, BK = 16, LDA = 132; // pad: 16B-aligned rows, <=2-way conflicts
  __shared__ float As[BK][LDA];
  __shared__ float Bs[BK][LDA];
  const int b  = blockIdx.y;
  const int m0 = (blockIdx.x >> 1) * BM;
  const int n0 = (blockIdx.x & 1) * BN;
  const int tid = threadIdx.x;
  const int ty = tid >> 4, tx = tid & 15;
  const int lrow = tid >> 2, lkq = tid & 3;
  const float* Ab = C  + (size_t)b * T * D;
  const float* Bq = Qp + (size_t)b * J * D;
  float acc[8][8] = {{0.f}};
  for (int k0 = 0; k0 < D; k0 += BK) {
    float4 a0 = *(const float4*)(Ab + (size_t)(m0 + lrow     ) * D + k0 + lkq * 4);
    float4 a1 = *(const float4*)(Ab + (size_t)(m0 + lrow + 64) * D + k0 + lkq * 4);
    float4 b0 = *(const float4*)(Bq + (size_t)(n0 + lrow     ) * D + k0 + lkq * 4);
    float4 b1 = *(const float4*)(Bq + (size_t)(n0 + lrow + 64) * D + k0 + lkq * 4);
    __syncthreads();
    const int kb = lkq * 4;
    As[kb+0][lrow] = a0.x; As[kb+1][lrow] = a0.y; As[kb+2][lrow] = a0.z; As[kb+3][lrow] = a0.w;
    As[kb+0][lrow+64] = a1.x; As[kb+1][lrow+64] = a1.y; As[kb+2][lrow+64] = a1.z; As[kb+3][lrow+64] = a1.w;
    Bs[kb+0][lrow] = b0.x; Bs[kb+1][lrow] = b0.y; Bs[kb+2][lrow] = b0.z; Bs[kb+3][lrow] = b0.w;
    Bs[kb+0][lrow+64] = b1.x; Bs[kb+1][lrow+64] = b1.y; Bs[kb+2][lrow+64] = b1.z; Bs[kb+3][lrow+64] = b1.w;
    __syncthreads();
    #pragma unroll
    for (int kk = 0; kk < BK; ++kk) {
      float4 av0 = *(const float4*)&As[kk][ty * 8];
      float4 av1 = *(const float4*)&As[kk][ty * 8 + 4];
      float4 bv0 = *(const float4*)&Bs[kk][tx * 8];
      float4 bv1 = *(const float4*)&Bs[kk][tx * 8 + 4];
      float a[8]  = {av0.x, av0.y, av0.z, av0.w, av1.x, av1.y, av1.z, av1.w};
      float bb[8] = {bv0.x, bv0.y, bv0.z, bv0.w, bv1.x, bv1.y, bv1.z, bv1.w};
      #pragma unroll
      for (int i = 0; i < 8; ++i)
        #pragma unroll
        for (int jj = 0; jj < 8; ++jj)
          acc[i][jj] = fmaf(a[i], bb[jj], acc[i][jj]);
    }
  }
  float rv[8], cv[8];
  #pragma unroll
  for (int i = 0; i < 8; ++i) rv[i] = rt[b * T + m0 + ty * 8 + i];
  #pragma unroll
  for (int jj = 0; jj < 8; ++jj) cv[jj] = ct[b * J + n0 + tx * 8 + jj];
  float* Sb = S + (size_t)b * T * J;
  #pragma unroll
  for (int i = 0; i < 8; ++i) {
    float o[8];
    #pragma unroll
    for (int jj = 0; jj < 8; ++jj) o[jj] = acc[i][jj] + rv[i] + cv[jj];
    *(float4*)(Sb + (size_t)(m0 + ty*8 + i) * J + n0 + tx*8)     = make_float4(o[0], o[1], o[2], o[3]);
    *(float4*)(Sb + (size_t)(m0 + ty*8 + i) * J + n0 + tx*8 + 4) = make_float4(o[4], o[5], o[6], o[7]);
  }
}

// ---------- per-(b,j) online softmax stats over t (partial over 64 t) ----------
__global__ void k_colstats_part(const float* __restrict__ S,
                                float* __restrict__ pm, float* __restrict__ pl) {
  int b = blockIdx.y, chunk = blockIdx.x, j = threadIdx.x;
  const float* Sb = S + (size_t)b * T * J + (size_t)chunk * 64 * J + j;
  float m = -INFINITY, l = 0.f;
  for (int t = 0; t < 64; ++t) {
    float x = Sb[(size_t)t * J];
    float mn = fmaxf(m, x);
    l = l * __expf(m - mn) + __expf(x - mn);
    m = mn;
  }
  pm[((size_t)b * 16 + chunk) * J + j] = m;
  pl[((size_t)b * 16 + chunk) * J + j] = l;
}

__global__ void k_colcombine(const float* __restrict__ pm, const float* __restrict__ pl,
                             float* __restrict__ mcol, float* __restrict__ invl) {
  int b = blockIdx.x, j = threadIdx.x;
  float m = -INFINITY, l = 0.f;
  for (int c = 0; c < 16; ++c) {
    float pmv = pm[((size_t)b * 16 + c) * J + j];
    float plv = pl[((size_t)b * 16 + c) * J + j];
    float mn = fmaxf(m, pmv);
    l = l * __expf(m - mn) + plv * __expf(pmv - mn);
    m = mn;
  }
  mcol[b * J + j] = m;
  invl[b * J + j] = 1.f / l;
}

// ---------- rowmax[b,t] = max_j S ----------
__global__ void k_rowmax(const float* __restrict__ S, float* __restrict__ rm) {
  int row = blockIdx.x * 4 + (threadIdx.x >> 6);
  int lane = threadIdx.x & 63;
  float4 v = ((const float4*)(S + (size_t)row * J))[lane];
  float m = fmaxf(fmaxf(v.x, v.y), fmaxf(v.z, v.w));
  #pragma unroll
  for (int off = 32; off; off >>= 1) m = fmaxf(m, __shfl_down(m, off));
  if (lane == 0) rm[row] = m;
}

// ---------- b_t = softmax over t of rowmax ----------
__global__ void k_btsm(const float* __restrict__ rm, float* __restrict__ bt) {
  __shared__ float red[4];
  int b = blockIdx.x, tid = threadIdx.x;
  int wid = tid >> 6, lane = tid & 63;
  float4 x = ((const float4*)(rm + (size_t)b * T))[tid];
  float m = fmaxf(fmaxf(x.x, x.y), fmaxf(x.z, x.w));
  #pragma unroll
  for (int off = 32; off; off >>= 1) m = fmaxf(m, __shfl_down(m, off));
  if (lane == 0) red[wid] = m;
  __syncthreads();
  float M = fmaxf(fmaxf(red[0], red[1]), fmaxf(red[2], red[3]));
  float e0 = __expf(x.x - M), e1 = __expf(x.y - M), e2 = __expf(x.z - M), e3 = __expf(x.w - M);
  float s = e0 + e1 + e2 + e3;
  #pragma unroll
  for (int off = 32; off; off >>= 1) s += __shfl_down(s, off);
  __syncthreads();
  if (lane == 0) red[wid] = s;
  __syncthreads();
  float inv = 1.f / (red[0] + red[1] + red[2] + red[3]);
  ((float4*)(bt + (size_t)b * T))[tid] = make_float4(e0 * inv, e1 * inv, e2 * inv, e3 * inv);
}

// ---------- h[b,d] = sum_t bt * context ----------
__global__ void k_h(const float* __restrict__ C, const float* __restrict__ bt,
                    float* __restrict__ h) {
  int b = blockIdx.y, chunk = blockIdx.x, tid = threadIdx.x;
  const float* Cb = C + (size_t)b * T * D + (size_t)chunk * 128 * D;
  const float* wb = bt + b * T + chunk * 128;
  float2 acc = make_float2(0.f, 0.f);
  for (int t = 0; t < 128; ++t) {
    float w = wb[t];
    float2 v = ((const float2*)(Cb + (size_t)t * D))[tid];
    acc.x = fmaf(w, v.x, acc.x);
    acc.y = fmaf(w, v.y, acc.y);
  }
  atomicAdd(&h[b * D + tid * 2],     acc.x);
  atomicAdd(&h[b * D + tid * 2 + 1], acc.y);
}

// ---------- U = P @ query fused with G assembly ----------
__global__ __launch_bounds__(256)
void k_uepi(const float* __restrict__ S, const float* __restrict__ Q,
            const float* __restrict__ mcol, const float* __restrict__ invl,
            const float* __restrict__ C, const float* __restrict__ h,
            float* __restrict__ out) {
  constexpr int BM = 128, BN = 128, BK = 16, LDA = 132;
  __shared__ float As[BK][LDA];
  __shared__ float Bs[BK][LDA];
  const int b  = blockIdx.y;
  const int m0 = (blockIdx.x >> 2) * BM;   // 8 m-blocks
  const int n0 = (blockIdx.x & 3) * BN;    // 4 n-blocks (N=512)
  const int tid = threadIdx.x;
  const int ty = tid >> 4, tx = tid & 15;
  const int lrow = tid >> 2, lkq = tid & 3;  // A-tile loader
  const int jr = tid >> 5, dq = tid & 31;    // B-tile loader
  const float* Sb = S + (size_t)b * T * J;
  const float* Qb = Q + (size_t)b * J * D;
  const float* mb = mcol + b * J;
  const float* ib = invl + b * J;
  float acc[8][8] = {{0.f}};
  for (int k0 = 0; k0 < J; k0 += BK) {
    float4 s0 = *(const float4*)(Sb + (size_t)(m0 + lrow     ) * J + k0 + lkq * 4);
    float4 s1 = *(const float4*)(Sb + (size_t)(m0 + lrow + 64) * J + k0 + lkq * 4);
    float4 mv = *(const float4*)(mb + k0 + lkq * 4);
    float4 iv = *(const float4*)(ib + k0 + lkq * 4);
    float4 q0 = *(const float4*)(Qb + (size_t)(k0 + jr    ) * D + n0 + dq * 4);
    float4 q1 = *(const float4*)(Qb + (size_t)(k0 + jr + 8) * D + n0 + dq * 4);
    float p0x = __expf(s0.x - mv.x) * iv.x, p0y = __expf(s0.y - mv.y) * iv.y;
    float p0z = __expf(s0.z - mv.z) * iv.z, p0w = __expf(s0.w - mv.w) * iv.w;
    float p1x = __expf(s1.x - mv.x) * iv.x, p1y = __expf(s1.y - mv.y) * iv.y;
    float p1z = __expf(s1.z - mv.z) * iv.z, p1w = __expf(s1.w - mv.w) * iv.w;
    __syncthreads();
    const int kb = lkq * 4;
    As[kb+0][lrow] = p0x; As[kb+1][lrow] = p0y; As[kb+2][lrow] = p0z; As[kb+3][lrow] = p0w;
    As[kb+0][lrow+64] = p1x; As[kb+1][lrow+64] = p1y; As[kb+2][lrow+64] = p1z; As[kb+3][lrow+64] = p1w;
    *(float4*)&Bs[jr    ][dq * 4] = q0;
    *(float4*)&Bs[jr + 8][dq * 4] = q1;
    __syncthreads();
    #pragma unroll
    for (int kk = 0; kk < BK; ++kk) {
      float4 av0 = *(const float4*)&As[kk][ty * 8];
      float4 av1 = *(const float4*)&As[kk][ty * 8 + 4];
      float4 bv0 = *(const float4*)&Bs[kk][tx * 8];
      float4 bv1 = *(const float4*)&Bs[kk][tx * 8 + 4];
      float a[8]  = {av0.x, av0.y, av0.z, av0.w, av1.x, av1.y, av1.z, av1.w};
      float bb[8] = {bv0.x, bv0.y, bv0.z, bv0.w, bv1.x, bv1.y, bv1.z, bv1.w};
      #pragma unroll
      for (int i = 0; i < 8; ++i)
        #pragma unroll
        for (int jj = 0; jj < 8; ++jj)
          acc[i][jj] = fmaf(a[i], bb[jj], acc[i][jj]);
    }
  }
  // epilogue: G = [c, U, c*U, c*h]
  float hv[8];
  #pragma unroll
  for (int e = 0; e < 8; ++e) hv[e] = h[b * D + n0 + tx * 8 + e];
  #pragma unroll
  for (int i = 0; i < 8; ++i) {
    int tm = m0 + ty * 8 + i;
    const float* crow = C + ((size_t)b * T + tm) * D + n0 + tx * 8;
    float4 c0 = *(const float4*)crow;
    float4 c1 = *(const float4*)(crow + 4);
    float* orow = out + ((size_t)b * T + tm) * (size_t)(4 * D);
    int nd = n0 + tx * 8;
    float4 u0 = make_float4(acc[i][0], acc[i][1], acc[i][2], acc[i][3]);
    float4 u1 = make_float4(acc[i][4], acc[i][5], acc[i][6], acc[i][7]);
    *(float4*)(orow + nd)     = c0;
    *(float4*)(orow + nd + 4) = c1;
    *(float4*)(orow + D + nd)     = u0;
    *(float4*)(orow + D + nd + 4) = u1;
    *(float4*)(orow + 2*D + nd)     = make_float4(c0.x*u0.x, c0.y*u0.y, c0.z*u0.z, c0.w*u0.w);
    *(float4*)(orow + 2*D + nd + 4) = make_float4(c1.x*u1.x, c1.y*u1.y, c1.z*u1.z, c1.w*u1.w);
    *(float4*)(orow + 3*D + nd)     = make_float4(c0.x*hv[0], c0.y*hv[1], c0.z*hv[2], c0.w*hv[3]);
    *(float4*)(orow + 3*D + nd + 4) = make_float4(c1.x*hv[4], c1.y*hv[5], c1.z*hv[6], c1.w*hv[7]);
  }
}

extern "C" void kernel_launch(void* const* d_in, const int* in_sizes, int n_in,
                              void* d_out, int out_size, void* d_ws, size_t ws_size,
                              hipStream_t stream) {
  const float* context = (const float*)d_in[0];
  const float* query   = (const float*)d_in[1];
  const float* w_alpha = (const float*)d_in[2];
  float* out = (float*)d_out;
  float* ws  = (float*)d_ws;

  float* S    = ws + OFF_S;
  float* Qp   = ws + OFF_QP;
  float* rt   = ws + OFF_RT;
  float* ct   = ws + OFF_CT;
  float* mcol = ws + OFF_M;
  float* invl = ws + OFF_IL;
  float* rm   = ws + OFF_RM;
  float* bt   = ws + OFF_BT;
  float* h    = ws + OFF_H;
  float* pm   = ws + OFF_PM;
  float* pl   = ws + OFF_PL;

  hipMemsetAsync(h, 0, (size_t)B * D * sizeof(float), stream);

  k_rowdot<<<dim3(B * T / 4), 256, 0, stream>>>(context, w_alpha, rt, B * T);
  k_prep  <<<dim3(B * J / 4), 256, 0, stream>>>(query, w_alpha, ct, Qp);
  k_sgemm <<<dim3(16, B), 256, 0, stream>>>(context, Qp, rt, ct, S);
  k_colstats_part<<<dim3(16, B), 256, 0, stream>>>(S, pm, pl);
  k_colcombine   <<<dim3(B), 256, 0, stream>>>(pm, pl, mcol, invl);
  k_rowmax<<<dim3(B * T / 4), 256, 0, stream>>>(S, rm);
  k_btsm  <<<dim3(B), 256, 0, stream>>>(rm, bt);
  k_h     <<<dim3(8, B), 256, 0, stream>>>(context, bt, h);
  k_uepi  <<<dim3(32, B), 256, 0, stream>>>(S, query, mcol, invl, context, h, out);
}